// Round 13
// baseline (643.005 us; speedup 1.0000x reference)
//
#include <hip/hip_runtime.h>
#include <math.h>

#define NB   8
#define NC   192
#define NPIX 3136
#define NPAD 3200
#define GRID_LL (NB*98)    // 784: M-tile 32
#define NIT  25
#define NSP  8
#define GRID_KNN (NB*NIT*NSP)   // 1600
#define GRID_MSG (NB*196)  // 1568
#define FINF 3.4e38f

typedef _Float16 f16x8 __attribute__((ext_vector_type(8)));
typedef float   f32x16 __attribute__((ext_vector_type(16)));

__device__ __forceinline__ float gelu_f(float x){
    float u = 0.7978845608028654f * (x + 0.044715f * x * x * x);
    return 0.5f * x * (1.0f + tanhf(u));
}

// ---------------- min-lex top9 (exact rescore) ----------------
#define LESS9(da,ia,db,ib) ((da) < (db) || ((da) == (db) && (ia) < (ib)))
#define CSW9(a,ia,b,ib) { bool sw_ = LESS9(b,ib,a,ia); float tf_=(a); int ti_=(ia); \
    (a) = sw_? (b) : (a); (ia) = sw_? (ib) : (ia); (b) = sw_? tf_ : (b); (ib) = sw_? ti_ : (ib); }

struct Top9 {
    float d0,d1,d2,d3,d4,d5,d6,d7,d8;
    int   j0,j1,j2,j3,j4,j5,j6,j7,j8;
    __device__ __forceinline__ void init(){
        d0=d1=d2=d3=d4=d5=d6=d7=d8=FINF;
        j0=j1=j2=j3=j4=j5=j6=j7=j8=0x7FFFFFFF;
    }
    __device__ __forceinline__ void insert(float nd, int ni){
        if (!LESS9(nd, ni, d8, j8)) return;
        d8 = nd; j8 = ni;
        CSW9(d7,j7,d8,j8); CSW9(d6,j6,d7,j7); CSW9(d5,j5,d6,j6); CSW9(d4,j4,d5,j5);
        CSW9(d3,j3,d4,j4); CSW9(d2,j2,d3,j3); CSW9(d1,j1,d2,j2); CSW9(d0,j0,d1,j1);
    }
};

// ---------------- u32-key top12 (knn screen) ----------------
__device__ __forceinline__ unsigned f2mono(float e){
    unsigned u = __float_as_uint(e);
    return u ^ ((unsigned)((int)u >> 31) | 0x80000000u);
}
// inverse of f2mono
__device__ __forceinline__ float unmono(unsigned m){
    return __uint_as_float(m ^ ((unsigned)(((int)~m) >> 31) | 0x80000000u));
}

#define CSK(a,b) { unsigned h_ = (a) > (b) ? (a) : (b); unsigned l_ = (a) > (b) ? (b) : (a); (a) = h_; (b) = l_; }
#define INSKEY(x_) if ((x_) > t_k11){ t_k11 = (x_); \
    CSK(t_k10,t_k11) CSK(t_k9,t_k10) CSK(t_k8,t_k9) CSK(t_k7,t_k8) \
    CSK(t_k6,t_k7) CSK(t_k5,t_k6) CSK(t_k4,t_k5) CSK(t_k3,t_k4) \
    CSK(t_k2,t_k3) CSK(t_k1,t_k2) CSK(t_k0,t_k1) }

#define KQ(A,Q) { \
    unsigned q0_ = (f2mono(A[4*(Q)+0]) & 0xFFFFF000u) | (unsigned)(jinvb_ - 8*(Q)    ); \
    unsigned q1_ = (f2mono(A[4*(Q)+1]) & 0xFFFFF000u) | (unsigned)(jinvb_ - 8*(Q) - 1); \
    unsigned q2_ = (f2mono(A[4*(Q)+2]) & 0xFFFFF000u) | (unsigned)(jinvb_ - 8*(Q) - 2); \
    unsigned q3_ = (f2mono(A[4*(Q)+3]) & 0xFFFFF000u) | (unsigned)(jinvb_ - 8*(Q) - 3); \
    unsigned qa_ = q0_ > q1_ ? q0_ : q1_; \
    unsigned qb_ = q2_ > q3_ ? q2_ : q3_; \
    unsigned qm_ = qa_ > qb_ ? qa_ : qb_; \
    if (qm_ > t_k11){ INSKEY(q0_) INSKEY(q1_) INSKEY(q2_) INSKEY(q3_) } }

#define AMAX16(A) fmaxf(fmaxf(fmaxf(fmaxf(A[0],A[1]),fmaxf(A[2],A[3])),fmaxf(fmaxf(A[4],A[5]),fmaxf(A[6],A[7]))), \
                        fmaxf(fmaxf(fmaxf(A[8],A[9]),fmaxf(A[10],A[11])),fmaxf(fmaxf(A[12],A[13]),fmaxf(A[14],A[15]))))

// float screen first: build keys only if the acc can possibly insert
#define INSACCK(A,JS) { float am_ = AMAX16(A); \
    if (am_ >= thrf){ int jinvb_ = 4095 - (jg + (JS)*32 + 4*h); \
        KQ(A,0) KQ(A,1) KQ(A,2) KQ(A,3) } }

#define MF(ACC,AO,BO) ACC = __builtin_amdgcn_mfma_f32_32x32x16_f16(AO,BO,ACC,0,0,0);
#define ZERO16 {0,0,0,0,0,0,0,0,0,0,0,0,0,0,0,0}

// ---------------------------------------------------------------------------
// Weight transpose: WT[k][n] = W[n][k]. 32x32 tiles via LDS.
// ---------------------------------------------------------------------------
__global__ __launch_bounds__(256) void wt_kernel(
    const float* __restrict__ W1, const float* __restrict__ W2,
    const float* __restrict__ Wg, const float* __restrict__ W3,
    const float* __restrict__ W4,
    float* __restrict__ W1T, float* __restrict__ W2T, float* __restrict__ WgT,
    float* __restrict__ W3T, float* __restrict__ W4T)
{
    __shared__ float tile[32*33];
    int t = blockIdx.x;
    const float* src; float* dst; int Kin;
    if (t < 36)      { src = W1; dst = W1T; Kin = 192; }
    else if (t < 72) { src = W2; dst = W2T; Kin = 192; t -= 36; }
    else if (t < 144){ src = Wg; dst = WgT; Kin = 384; t -= 72; }
    else if (t < 180){ src = W3; dst = W3T; Kin = 192; t -= 144; }
    else             { src = W4; dst = W4T; Kin = 192; t -= 180; }
    int ntc = Kin >> 5;
    int tr = t / ntc, tc = t - tr*ntc;
    int tid = threadIdx.x;
    {
        int i = tid >> 3, j4 = (tid & 7)*4;
        float4 v = *(const float4*)&src[(size_t)(tr*32 + i)*Kin + tc*32 + j4];
        tile[i*33 + j4+0] = v.x; tile[i*33 + j4+1] = v.y;
        tile[i*33 + j4+2] = v.z; tile[i*33 + j4+3] = v.w;
    }
    __syncthreads();
    {
        int j = tid >> 3, i4 = (tid & 7)*4;
        float4 o = make_float4(tile[(i4+0)*33 + j], tile[(i4+1)*33 + j],
                               tile[(i4+2)*33 + j], tile[(i4+3)*33 + j]);
        *(float4*)&dst[(size_t)(tc*32 + j)*192 + tr*32 + i4] = o;
    }
}

// ---------------------------------------------------------------------------
// Fused GEMM + lorentz_linear, col-major activations, REGISTER PREFETCH:
// kt+1's A/W tiles load into regs while kt computes (T14 async-stage split).
// ---------------------------------------------------------------------------
template<int K, bool DUAL, bool AX, bool AR>
__global__ __launch_bounds__(256, 3) void ll2_kernel(
    const float* __restrict__ A0, const float* __restrict__ A1,
    const float* __restrict__ WT, const float* __restrict__ bias,
    const float* __restrict__ sptr, const float* __restrict__ Xres,
    const float* __restrict__ Rcm,
    float* __restrict__ OutCM, float* __restrict__ Hrm)
{
    __shared__ float lA[32*36];    // [kk][mm]
    __shared__ float lW[32*196];   // [kk][nn]

    const int tid = threadIdx.x;
    const int tx = tid & 15, ty = tid >> 4;
    const int bid = blockIdx.x;
    const int b  = bid / 98;
    const int n0 = (bid % 98) * 32;

    float acc[2][12];
    #pragma unroll
    for (int mi = 0; mi < 2; ++mi)
        #pragma unroll
        for (int j = 0; j < 12; ++j) acc[mi][j] = 0.f;

    float4 aReg;
    float4 wReg[6];

#define LOADA(KT) { int kk = tid >> 3; int m4 = (tid & 7) * 4; int c = (KT)*32 + kk; \
        const float* pl; \
        if (K > 192 && c >= 192) pl = A1 + ((size_t)b*192 + (c - 192))*NPIX; \
        else                     pl = A0 + ((size_t)b*192 + c)*NPIX; \
        aReg = *(const float4*)&pl[n0 + m4]; }
#define LOADW(KT) { \
        _Pragma("unroll") \
        for (int r = 0; r < 6; ++r){ \
            int e  = tid + r*256; \
            int kk = e / 48; \
            int c4 = (e - kk*48) * 4; \
            wReg[r] = *(const float4*)&WT[(size_t)((KT)*32 + kk)*192 + c4]; } }

    LOADA(0) LOADW(0)

    for (int kt = 0; kt < K/32; ++kt){
        __syncthreads();
        {
            float4 v = aReg;
            v.x = gelu_f(v.x); v.y = gelu_f(v.y); v.z = gelu_f(v.z); v.w = gelu_f(v.w);
            int kk = tid >> 3, m4 = (tid & 7) * 4;
            *(float4*)&lA[kk*36 + m4] = v;
        }
        #pragma unroll
        for (int r = 0; r < 6; ++r){
            int e  = tid + r*256;
            int kk = e / 48;
            int c4 = (e - kk*48) * 4;
            *(float4*)&lW[kk*196 + c4] = wReg[r];
        }
        __syncthreads();
        if (kt + 1 < K/32){ LOADA(kt+1) LOADW(kt+1) }
        #pragma unroll
        for (int kk = 0; kk < 32; ++kk){
            float2 a2 = *(const float2*)&lA[kk*36 + ty*2];
            float4 w0 = *(const float4*)&lW[kk*196 + tx*12];
            float4 w1 = *(const float4*)&lW[kk*196 + tx*12 + 4];
            float4 w2 = *(const float4*)&lW[kk*196 + tx*12 + 8];
            float aw[2]  = {a2.x, a2.y};
            float wv[12] = {w0.x,w0.y,w0.z,w0.w, w1.x,w1.y,w1.z,w1.w, w2.x,w2.y,w2.z,w2.w};
            #pragma unroll
            for (int mi = 0; mi < 2; ++mi)
                #pragma unroll
                for (int j = 0; j < 12; ++j)
                    acc[mi][j] = fmaf(aw[mi], wv[j], acc[mi][j]);
        }
    }
#undef LOADA
#undef LOADW

    const int lane = tid & 63;
    float es = expf(sptr[0]);
    float bv[12];
    #pragma unroll
    for (int q = 0; q < 3; ++q){
        float4 t4 = *(const float4*)&bias[tx*12 + q*4];
        bv[q*4+0] = t4.x; bv[q*4+1] = t4.y; bv[q*4+2] = t4.z; bv[q*4+3] = t4.w;
    }
    #pragma unroll
    for (int mi = 0; mi < 2; ++mi){
        float part = 0.f;
        #pragma unroll
        for (int j = 0; j < 12; ++j){
            float y = acc[mi][j] + bv[j];
            acc[mi][j] = y;
            if (!(tx == 0 && j == 0)) part += y * y;
        }
        #pragma unroll
        for (int m = 1; m < 16; m <<= 1) part += __shfl_xor(part, m, 64);
        float y0   = __shfl(acc[mi][0], lane & 48, 64);
        float tval = es / (1.f + expf(-y0)) + 1.1f;
        float denom = fmaxf(part, 1e-8f);
        float sca  = (tval*tval - 1.f) / denom;
        float sqs  = sqrtf(sca);
        #pragma unroll
        for (int j = 0; j < 12; ++j){
            float o = acc[mi][j] * sqs;
            if (tx == 0 && j == 0) o = tval;
            acc[mi][j] = o;
        }
    }
    if (AX){
        #pragma unroll
        for (int j = 0; j < 12; ++j){
            int c = tx*12 + j;
            float2 xv = *(const float2*)&Xres[((size_t)b*192 + c)*NPIX + n0 + ty*2];
            acc[0][j] += xv.x; acc[1][j] += xv.y;
        }
    }
    if (AR){
        #pragma unroll
        for (int j = 0; j < 12; ++j){
            int c = tx*12 + j;
            float2 rv = *(const float2*)&Rcm[((size_t)b*192 + c)*NPIX + n0 + ty*2];
            acc[0][j] += rv.x; acc[1][j] += rv.y;
        }
    }
    #pragma unroll
    for (int j = 0; j < 12; ++j){
        int c = tx*12 + j;
        *(float2*)&OutCM[((size_t)b*192 + c)*NPIX + n0 + ty*2] = make_float2(acc[0][j], acc[1][j]);
    }
    if (DUAL){
        #pragma unroll
        for (int mi = 0; mi < 2; ++mi){
            #pragma unroll
            for (int q = 0; q < 3; ++q){
                float4 o = make_float4(acc[mi][q*4+0], acc[mi][q*4+1], acc[mi][q*4+2], acc[mi][q*4+3]);
                *(float4*)&Hrm[((size_t)b*NPIX + n0 + ty*2 + mi)*192 + tx*12 + q*4] = o;
            }
        }
    }
}

// ---------------------------------------------------------------------------
// conv: Hrm fp32 rows (stride 192) -> Xh/Xl fp16 hi/lo, S2 packed(-sq/2), SQf.
// ---------------------------------------------------------------------------
__device__ __forceinline__ unsigned pack2(float a, float b, unsigned &lo){
    union { _Float16 f; unsigned short u; } ha, hb, la, lb;
    ha.f = (_Float16)a; hb.f = (_Float16)b;
    float ra = a - (float)ha.f, rb = b - (float)hb.f;
    la.f = (_Float16)ra; lb.f = (_Float16)rb;
    lo = (unsigned)la.u | ((unsigned)lb.u << 16);
    return (unsigned)ha.u | ((unsigned)hb.u << 16);
}

__global__ __launch_bounds__(256) void conv_kernel(
    const float* __restrict__ H, unsigned short* __restrict__ Xh,
    unsigned short* __restrict__ Xl, unsigned* __restrict__ S2,
    float* __restrict__ SQf)
{
    const int tid = threadIdx.x;
    const int r = blockIdx.x*64 + (tid >> 2);
    const int b = r / NPAD, rl = r - b*NPAD;
    const int part = tid & 3;
    const size_t ob = ((size_t)b*NPAD + rl)*192 + part*48;

    if (rl < NPIX){
        const float* src = H + ((size_t)b*NPIX + rl)*192 + part*48;
        float s = 0.f;
        #pragma unroll
        for (int q = 0; q < 6; ++q){
            float4 v0 = *(const float4*)&src[q*8];
            float4 v1 = *(const float4*)&src[q*8 + 4];
            s = fmaf(v0.x,v0.x, fmaf(v0.y,v0.y, fmaf(v0.z,v0.z, fmaf(v0.w,v0.w, s))));
            s = fmaf(v1.x,v1.x, fmaf(v1.y,v1.y, fmaf(v1.z,v1.z, fmaf(v1.w,v1.w, s))));
            uint4 hv, lv;
            hv.x = pack2(v0.x, v0.y, lv.x);
            hv.y = pack2(v0.z, v0.w, lv.y);
            hv.z = pack2(v1.x, v1.y, lv.z);
            hv.w = pack2(v1.z, v1.w, lv.w);
            *(uint4*)&Xh[ob + q*8] = hv;
            *(uint4*)&Xl[ob + q*8] = lv;
        }
        s += __shfl_xor(s, 1, 64);
        s += __shfl_xor(s, 2, 64);
        if (part == 0){
            SQf[(size_t)b*NPIX + rl] = s;
            float s2 = -0.5f * s;
            union { _Float16 f; unsigned short u; } hh, ll;
            hh.f = (_Float16)s2;
            float rr = s2 - (float)hh.f;
            ll.f = (_Float16)rr;
            S2[(size_t)b*NPAD + rl] = (unsigned)hh.u | ((unsigned)ll.u << 16);
        }
    } else {
        uint4 z = make_uint4(0,0,0,0);
        #pragma unroll
        for (int q = 0; q < 6; ++q){
            *(uint4*)&Xh[ob + q*8] = z;
            *(uint4*)&Xl[ob + q*8] = z;
        }
        if (part == 0){
            union { _Float16 f; unsigned short u; } p;
            p.f = (_Float16)(-30000.0f);
            S2[(size_t)b*NPAD + rl] = (unsigned)p.u;
        }
    }
}

// ---------------------------------------------------------------------------
// MFMA kNN screen with float pre-screen before key build.
// ---------------------------------------------------------------------------
__global__ __launch_bounds__(256) __attribute__((amdgpu_waves_per_eu(2))) void knn_kernel(
    const unsigned short* __restrict__ Xh, const unsigned short* __restrict__ Xl,
    const unsigned* __restrict__ S2, unsigned* __restrict__ PK)
{
    __shared__ uint4 lds[2560];

    const int tid  = threadIdx.x;
    const int lane = tid & 63;
    const int w    = tid >> 6;
    const int l31  = lane & 31;
    const int h    = lane >> 5;
    const int bid  = blockIdx.x;
    const int b    = bid & 7;
    const int t2   = bid >> 3;
    const int itile = t2 >> 3;
    const int sp    = t2 & 7;
    const int i0    = itile * 128;
    const int g0 = (sp*25)/8, g1 = ((sp+1)*25)/8;
    const size_t rowb = (size_t)b * NPAD;

    unsigned t_k0=0,t_k1=0,t_k2=0,t_k3=0,t_k4=0,t_k5=0,
             t_k6=0,t_k7=0,t_k8=0,t_k9=0,t_k10=0,t_k11=0;
    float thrf = -FINF;

    for (int g = g0; g < g1; ++g){
        const int jg = g*128;
        f32x16 acc0 = ZERO16, acc1 = ZERO16, acc2 = ZERO16, acc3 = ZERO16;

        for (int kc = 0; kc < 6; ++kc){
            __syncthreads();
            #pragma unroll
            for (int rr = 0; rr < 8; ++rr){
                int u   = tid + rr*256;
                int arr = u >> 9;
                int rs  = (u >> 2) & 127;
                int seg = u & 3;
                int row = (arr < 2) ? (jg + rs) : (i0 + rs);
                const unsigned short* sptr = (arr & 1) ? Xl : Xh;
                uint4 v = *(const uint4*)&sptr[(rowb + row)*192 + kc*32 + seg*8];
                lds[arr*640 + rs*5 + seg] = v;
            }
            __syncthreads();
            #pragma unroll
            for (int ks = 0; ks < 2; ++ks){
                int kq  = ks*2 + h;
                int rb  = l31*5 + kq;
                f16x8 bh = __builtin_bit_cast(f16x8, lds[1280 + w*160 + rb]);
                f16x8 bl = __builtin_bit_cast(f16x8, lds[1920 + w*160 + rb]);
                f16x8 a0h = __builtin_bit_cast(f16x8, lds[      0 + rb]);
                f16x8 a0l = __builtin_bit_cast(f16x8, lds[640 +   0 + rb]);
                MF(acc0, a0h, bh) MF(acc0, a0l, bh) MF(acc0, a0h, bl)
                f16x8 a1h = __builtin_bit_cast(f16x8, lds[      160 + rb]);
                f16x8 a1l = __builtin_bit_cast(f16x8, lds[640 + 160 + rb]);
                MF(acc1, a1h, bh) MF(acc1, a1l, bh) MF(acc1, a1h, bl)
                f16x8 a2h = __builtin_bit_cast(f16x8, lds[      320 + rb]);
                f16x8 a2l = __builtin_bit_cast(f16x8, lds[640 + 320 + rb]);
                MF(acc2, a2h, bh) MF(acc2, a2l, bh) MF(acc2, a2h, bl)
                f16x8 a3h = __builtin_bit_cast(f16x8, lds[      480 + rb]);
                f16x8 a3l = __builtin_bit_cast(f16x8, lds[640 + 480 + rb]);
                MF(acc3, a3h, bh) MF(acc3, a3l, bh) MF(acc3, a3h, bl)
            }
        }

        {
            unsigned m  = (h == 0) ? 0xFFFFFFFFu : 0u;
            unsigned om = 0x3C00u & m;
            f16x8 one = __builtin_bit_cast(f16x8, make_uint4(om, 0, 0, 0));
            unsigned s0 = S2[rowb + jg +  0 + l31];
            unsigned s1 = S2[rowb + jg + 32 + l31];
            unsigned s2 = S2[rowb + jg + 64 + l31];
            unsigned s3 = S2[rowb + jg + 96 + l31];
            f16x8 a;
            a = __builtin_bit_cast(f16x8, make_uint4((s0 & 0xFFFFu) & m, 0,0,0)); MF(acc0, a, one)
            a = __builtin_bit_cast(f16x8, make_uint4((s0 >> 16)     & m, 0,0,0)); MF(acc0, a, one)
            a = __builtin_bit_cast(f16x8, make_uint4((s1 & 0xFFFFu) & m, 0,0,0)); MF(acc1, a, one)
            a = __builtin_bit_cast(f16x8, make_uint4((s1 >> 16)     & m, 0,0,0)); MF(acc1, a, one)
            a = __builtin_bit_cast(f16x8, make_uint4((s2 & 0xFFFFu) & m, 0,0,0)); MF(acc2, a, one)
            a = __builtin_bit_cast(f16x8, make_uint4((s2 >> 16)     & m, 0,0,0)); MF(acc2, a, one)
            a = __builtin_bit_cast(f16x8, make_uint4((s3 & 0xFFFFu) & m, 0,0,0)); MF(acc3, a, one)
            a = __builtin_bit_cast(f16x8, make_uint4((s3 >> 16)     & m, 0,0,0)); MF(acc3, a, one)
        }

        INSACCK(acc0, 0)
        INSACCK(acc1, 1)
        INSACCK(acc2, 2)
        INSACCK(acc3, 3)
        thrf = (t_k11 != 0u) ? unmono(t_k11 & 0xFFFFF000u) : -FINF;
    }

    #define MRGK(Kk) { unsigned ok_ = __shfl((int)(Kk), lane ^ 32, 64); \
                      if (lane < 32) { INSKEY((unsigned)ok_) } }
    MRGK(t_k0) MRGK(t_k1) MRGK(t_k2) MRGK(t_k3) MRGK(t_k4) MRGK(t_k5)
    MRGK(t_k6) MRGK(t_k7) MRGK(t_k8) MRGK(t_k9) MRGK(t_k10) MRGK(t_k11)

    if (lane < 32){
        size_t po = ((size_t)(t2*8 + b)*128 + (size_t)w*32 + l31)*12;
        PK[po+ 0] = t_k0;  PK[po+ 1] = t_k1;  PK[po+ 2] = t_k2;  PK[po+ 3] = t_k3;
        PK[po+ 4] = t_k4;  PK[po+ 5] = t_k5;  PK[po+ 6] = t_k6;  PK[po+ 7] = t_k7;
        PK[po+ 8] = t_k8;  PK[po+ 9] = t_k9;  PK[po+10] = t_k10; PK[po+11] = t_k11;
    }
}

// ---------------------------------------------------------------------------
// 8-way key merge -> top-12 -> exact fp32 rescore -> top-9 -> max-message.
// Hrm stride 192; msg written COL-MAJOR to Msg [b][192][n].
// ---------------------------------------------------------------------------
__global__ __launch_bounds__(256) void merge_msg_kernel(
    const float* __restrict__ H, const float* __restrict__ SQf,
    const unsigned* __restrict__ PK, float* __restrict__ Msg)
{
    __shared__ float liX[16*196];
    __shared__ unsigned kv[1600];
    __shared__ float cd[192];
    __shared__ int   cidx[192];
    __shared__ int   fidx[144];

    const int tid = threadIdx.x;
    const int bid = blockIdx.x;
    const int b  = bid / 196;
    const int i0 = (bid % 196) * 16;
    const int base = b * NPIX;

    #pragma unroll
    for (int k = 0; k < 3; ++k){
        int f = tid + k*256;
        int r = f / 48, c4 = f % 48;
        *(float4*)&liX[r*196 + c4*4] = *(const float4*)&H[(size_t)(base + i0 + r)*192 + c4*4];
    }
    if (tid < 128){
        int r = tid >> 3, sp = tid & 7;
        int i = i0 + r;
        size_t po = ((size_t)(((i>>7)*8 + sp)*8 + b)*128 + (i & 127))*12;
        #pragma unroll
        for (int q = 0; q < 3; ++q)
            *(uint4*)&kv[r*100 + sp*12 + q*4] = *(const uint4*)&PK[po + q*4];
    }
    __syncthreads();

    if (tid < 16){
        int r = tid;
        int h0=0,h1=0,h2=0,h3=0,h4=0,h5=0,h6=0,h7=0;
        #pragma unroll
        for (int p = 0; p < 12; ++p){
            unsigned bk = 0; int bs = 0;
#define HEADC(SP,HV) { \
            unsigned k_ = (HV < 12) ? kv[r*100 + SP*12 + HV] : 0u; \
            bool bt_ = k_ > bk; \
            bk = bt_? k_ : bk; bs = bt_? SP : bs; }
            HEADC(0,h0) HEADC(1,h1) HEADC(2,h2) HEADC(3,h3)
            HEADC(4,h4) HEADC(5,h5) HEADC(6,h6) HEADC(7,h7)
#undef HEADC
            cidx[r*12 + p] = 4095 - (int)(bk & 0xFFFu);
            h0 += (bs==0); h1 += (bs==1); h2 += (bs==2); h3 += (bs==3);
            h4 += (bs==4); h5 += (bs==5); h6 += (bs==6); h7 += (bs==7);
        }
    }
    __syncthreads();

    if (tid < 192){
        int r = tid / 12, p = tid - r*12;
        int j = cidx[r*12 + p];
        const float* hj = &H[(size_t)(base + j)*192];
        float dot = 0.f;
        #pragma unroll
        for (int q = 0; q < 48; ++q){
            float4 xv = *(const float4*)&liX[r*196 + q*4];
            float4 yv = *(const float4*)&hj[q*4];
            dot = fmaf(xv.x,yv.x, fmaf(xv.y,yv.y, fmaf(xv.z,yv.z, fmaf(xv.w,yv.w, dot))));
        }
        cd[r*12 + p] = SQf[base + j] - 2.f*dot;
    }
    __syncthreads();

    if (tid < 16){
        int r = tid;
        Top9 m; m.init();
        #pragma unroll
        for (int c = 0; c < 12; ++c) m.insert(cd[r*12 + c], cidx[r*12 + c]);
        fidx[r*9+0]=m.j0; fidx[r*9+1]=m.j1; fidx[r*9+2]=m.j2; fidx[r*9+3]=m.j3;
        fidx[r*9+4]=m.j4; fidx[r*9+5]=m.j5; fidx[r*9+6]=m.j6; fidx[r*9+7]=m.j7;
        fidx[r*9+8]=m.j8;
    }
    __syncthreads();

    int rr = tid & 15, part = tid >> 4;
    int ii = i0 + rr;
    int nbr[9];
    #pragma unroll
    for (int e = 0; e < 9; ++e) nbr[e] = fidx[rr*9 + e];
    #pragma unroll
    for (int q = 0; q < 3; ++q){
        float4 mv = make_float4(-FINF, -FINF, -FINF, -FINF);
        #pragma unroll
        for (int e = 0; e < 9; ++e){
            float4 v = *(const float4*)&H[(size_t)(base + nbr[e])*192 + part*12 + q*4];
            mv.x = fmaxf(mv.x, v.x); mv.y = fmaxf(mv.y, v.y);
            mv.z = fmaxf(mv.z, v.z); mv.w = fmaxf(mv.w, v.w);
        }
        float4 xi = *(const float4*)&liX[rr*196 + part*12 + q*4];
        float m0 = mv.x - xi.x, m1 = mv.y - xi.y, m2 = mv.z - xi.z, m3 = mv.w - xi.w;
        int c = part*12 + q*4;
        Msg[((size_t)b*192 + c+0)*NPIX + ii] = m0;
        Msg[((size_t)b*192 + c+1)*NPIX + ii] = m1;
        Msg[((size_t)b*192 + c+2)*NPIX + ii] = m2;
        Msg[((size_t)b*192 + c+3)*NPIX + ii] = m3;
    }
}

extern "C" void kernel_launch(void* const* d_in, const int* in_sizes, int n_in,
                              void* d_out, int out_size, void* d_ws, size_t ws_size,
                              hipStream_t stream)
{
    const float* x  = (const float*)d_in[0];
    const float* W1 = (const float*)d_in[1];
    const float* b1 = (const float*)d_in[2];
    const float* s1 = (const float*)d_in[3];
    const float* W2 = (const float*)d_in[4];
    const float* b2 = (const float*)d_in[5];
    const float* s2 = (const float*)d_in[6];
    const float* Wg = (const float*)d_in[7];
    const float* bg = (const float*)d_in[8];
    const float* sg = (const float*)d_in[9];
    const float* W3 = (const float*)d_in[10];
    const float* b3 = (const float*)d_in[11];
    const float* s3 = (const float*)d_in[12];
    const float* W4 = (const float*)d_in[13];
    const float* b4 = (const float*)d_in[14];
    const float* s4 = (const float*)d_in[15];

    const size_t PL = (size_t)25088*192;
    float* Hrm  = (float*)d_ws;
    float* X1cm = Hrm  + PL;
    float* T1cm = X1cm + PL;
    float* X2cm = T1cm + PL;
    float* MXr  = X2cm + PL;
    unsigned short* Xh = (unsigned short*)MXr;
    unsigned short* Xl = Xh + (size_t)NB*NPAD*192;
    float* Msg = MXr;
    unsigned* S2p = (unsigned*)(MXr + (size_t)NB*NPAD*192/2*2);
    float* SQf = (float*)(S2p + (size_t)NB*NPAD);
    float* W1T = SQf + (size_t)NB*NPIX;
    float* W2T = W1T + 36864;
    float* WgT = W2T + 36864;
    float* W3T = WgT + 73728;
    float* W4T = W3T + 36864;
    unsigned* PK = (unsigned*)X2cm;
    float* out = (float*)d_out;

    wt_kernel<<<216, 256, 0, stream>>>(W1, W2, Wg, W3, W4, W1T, W2T, WgT, W3T, W4T);
    // ffn_lorentz #1
    ll2_kernel<192, false, false, false><<<GRID_LL, 256, 0, stream>>>(x,    x,    W1T, b1, s1, nullptr, nullptr, T1cm, nullptr);
    ll2_kernel<192, true , true , false><<<GRID_LL, 256, 0, stream>>>(T1cm, T1cm, W2T, b2, s2, x,       nullptr, X1cm, Hrm);
    // graph conv
    conv_kernel<<<NB*NPAD/64, 256, 0, stream>>>(Hrm, Xh, Xl, S2p, SQf);
    knn_kernel<<<GRID_KNN, 256, 0, stream>>>(Xh, Xl, S2p, PK);
    merge_msg_kernel<<<GRID_MSG, 256, 0, stream>>>(Hrm, SQf, PK, Msg);
    ll2_kernel<384, false, false, false><<<GRID_LL, 256, 0, stream>>>(X1cm, Msg,  WgT, bg, sg, nullptr, nullptr, X2cm, nullptr);
    // ffn_lorentz #2 + final shortcut (output col-major = (B,C,H,W) native)
    ll2_kernel<192, false, false, false><<<GRID_LL, 256, 0, stream>>>(X2cm, X2cm, W3T, b3, s3, nullptr, nullptr, T1cm, nullptr);
    ll2_kernel<192, false, true , true ><<<GRID_LL, 256, 0, stream>>>(T1cm, T1cm, W4T, b4, s4, x,       X2cm,    out,  nullptr);
}

// Round 14
// 639.888 us; speedup vs baseline: 1.0049x; 1.0049x over previous
//
#include <hip/hip_runtime.h>
#include <math.h>

#define NB   8
#define NC   192
#define NPIX 3136
#define NPAD 3200
#define GRID_LL (NB*196)   // 1568: M-tile 16
#define NIT  25
#define NSP  4
#define GRID_KNN (NB*NIT*NSP)   // 800
#define GRID_MSG (NB*196)  // 1568
#define FINF 3.4e38f

typedef _Float16 f16x8 __attribute__((ext_vector_type(8)));
typedef float   f32x16 __attribute__((ext_vector_type(16)));

__device__ __forceinline__ float gelu_f(float x){
    float u = 0.7978845608028654f * (x + 0.044715f * x * x * x);
    return 0.5f * x * (1.0f + tanhf(u));
}

// ---------------- min-lex top9 (exact rescore) ----------------
#define LESS9(da,ia,db,ib) ((da) < (db) || ((da) == (db) && (ia) < (ib)))
#define CSW9(a,ia,b,ib) { bool sw_ = LESS9(b,ib,a,ia); float tf_=(a); int ti_=(ia); \
    (a) = sw_? (b) : (a); (ia) = sw_? (ib) : (ia); (b) = sw_? tf_ : (b); (ib) = sw_? ti_ : (ib); }

struct Top9 {
    float d0,d1,d2,d3,d4,d5,d6,d7,d8;
    int   j0,j1,j2,j3,j4,j5,j6,j7,j8;
    __device__ __forceinline__ void init(){
        d0=d1=d2=d3=d4=d5=d6=d7=d8=FINF;
        j0=j1=j2=j3=j4=j5=j6=j7=j8=0x7FFFFFFF;
    }
    __device__ __forceinline__ void insert(float nd, int ni){
        if (!LESS9(nd, ni, d8, j8)) return;
        d8 = nd; j8 = ni;
        CSW9(d7,j7,d8,j8); CSW9(d6,j6,d7,j7); CSW9(d5,j5,d6,j6); CSW9(d4,j4,d5,j5);
        CSW9(d3,j3,d4,j4); CSW9(d2,j2,d3,j3); CSW9(d1,j1,d2,j2); CSW9(d0,j0,d1,j1);
    }
};

// ---------------- u32-key top12 (knn screen) ----------------
__device__ __forceinline__ unsigned f2mono(float e){
    unsigned u = __float_as_uint(e);
    return u ^ ((unsigned)((int)u >> 31) | 0x80000000u);
}
__device__ __forceinline__ float unmono(unsigned m){
    return __uint_as_float(m ^ ((unsigned)(((int)~m) >> 31) | 0x80000000u));
}

#define CSK(a,b) { unsigned h_ = (a) > (b) ? (a) : (b); unsigned l_ = (a) > (b) ? (b) : (a); (a) = h_; (b) = l_; }
#define INSKEY(x_) if ((x_) > t_k11){ t_k11 = (x_); \
    CSK(t_k10,t_k11) CSK(t_k9,t_k10) CSK(t_k8,t_k9) CSK(t_k7,t_k8) \
    CSK(t_k6,t_k7) CSK(t_k5,t_k6) CSK(t_k4,t_k5) CSK(t_k3,t_k4) \
    CSK(t_k2,t_k3) CSK(t_k1,t_k2) CSK(t_k0,t_k1) }

#define KQ(A,Q) { \
    unsigned q0_ = (f2mono(A[4*(Q)+0]) & 0xFFFFF000u) | (unsigned)(jinvb_ - 8*(Q)    ); \
    unsigned q1_ = (f2mono(A[4*(Q)+1]) & 0xFFFFF000u) | (unsigned)(jinvb_ - 8*(Q) - 1); \
    unsigned q2_ = (f2mono(A[4*(Q)+2]) & 0xFFFFF000u) | (unsigned)(jinvb_ - 8*(Q) - 2); \
    unsigned q3_ = (f2mono(A[4*(Q)+3]) & 0xFFFFF000u) | (unsigned)(jinvb_ - 8*(Q) - 3); \
    unsigned qa_ = q0_ > q1_ ? q0_ : q1_; \
    unsigned qb_ = q2_ > q3_ ? q2_ : q3_; \
    unsigned qm_ = qa_ > qb_ ? qa_ : qb_; \
    if (qm_ > t_k11){ INSKEY(q0_) INSKEY(q1_) INSKEY(q2_) INSKEY(q3_) } }

#define AMAX16(A) fmaxf(fmaxf(fmaxf(fmaxf(A[0],A[1]),fmaxf(A[2],A[3])),fmaxf(fmaxf(A[4],A[5]),fmaxf(A[6],A[7]))), \
                        fmaxf(fmaxf(fmaxf(A[8],A[9]),fmaxf(A[10],A[11])),fmaxf(fmaxf(A[12],A[13]),fmaxf(A[14],A[15]))))

#define INSACCK(A,JS) { float am_ = AMAX16(A); \
    if (am_ >= thrf){ int jinvb_ = 4095 - (jg + (JS)*32 + 4*h); \
        KQ(A,0) KQ(A,1) KQ(A,2) KQ(A,3) } }

#define MF(ACC,AO,BO) ACC = __builtin_amdgcn_mfma_f32_32x32x16_f16(AO,BO,ACC,0,0,0);
#define ZERO16 {0,0,0,0,0,0,0,0,0,0,0,0,0,0,0,0}

// ---------------------------------------------------------------------------
// Weight transpose: WT[k][n] = W[n][k]. 32x32 tiles via LDS.
// ---------------------------------------------------------------------------
__global__ __launch_bounds__(256) void wt_kernel(
    const float* __restrict__ W1, const float* __restrict__ W2,
    const float* __restrict__ Wg, const float* __restrict__ W3,
    const float* __restrict__ W4,
    float* __restrict__ W1T, float* __restrict__ W2T, float* __restrict__ WgT,
    float* __restrict__ W3T, float* __restrict__ W4T)
{
    __shared__ float tile[32*33];
    int t = blockIdx.x;
    const float* src; float* dst; int Kin;
    if (t < 36)      { src = W1; dst = W1T; Kin = 192; }
    else if (t < 72) { src = W2; dst = W2T; Kin = 192; t -= 36; }
    else if (t < 144){ src = Wg; dst = WgT; Kin = 384; t -= 72; }
    else if (t < 180){ src = W3; dst = W3T; Kin = 192; t -= 144; }
    else             { src = W4; dst = W4T; Kin = 192; t -= 180; }
    int ntc = Kin >> 5;
    int tr = t / ntc, tc = t - tr*ntc;
    int tid = threadIdx.x;
    {
        int i = tid >> 3, j4 = (tid & 7)*4;
        float4 v = *(const float4*)&src[(size_t)(tr*32 + i)*Kin + tc*32 + j4];
        tile[i*33 + j4+0] = v.x; tile[i*33 + j4+1] = v.y;
        tile[i*33 + j4+2] = v.z; tile[i*33 + j4+3] = v.w;
    }
    __syncthreads();
    {
        int j = tid >> 3, i4 = (tid & 7)*4;
        float4 o = make_float4(tile[(i4+0)*33 + j], tile[(i4+1)*33 + j],
                               tile[(i4+2)*33 + j], tile[(i4+3)*33 + j]);
        *(float4*)&dst[(size_t)(tc*32 + j)*192 + tr*32 + i4] = o;
    }
}

// ---------------------------------------------------------------------------
// Fused GEMM + lorentz_linear, col-major activations, M-tile 16 (grid 1568).
// Each thread: 1 row (ty) x 12 cols (tx*12..+11).
// ---------------------------------------------------------------------------
template<int K, bool DUAL, bool AX, bool AR>
__global__ __launch_bounds__(256, 4) void ll2_kernel(
    const float* __restrict__ A0, const float* __restrict__ A1,
    const float* __restrict__ WT, const float* __restrict__ bias,
    const float* __restrict__ sptr, const float* __restrict__ Xres,
    const float* __restrict__ Rcm,
    float* __restrict__ OutCM, float* __restrict__ Hrm)
{
    __shared__ float lA[32*20];    // [kk][mm], pad 20
    __shared__ float lW[32*196];   // [kk][nn]

    const int tid = threadIdx.x;
    const int tx = tid & 15, ty = tid >> 4;
    const int bid = blockIdx.x;
    const int b  = bid / 196;
    const int n0 = (bid % 196) * 16;

    float acc[12];
    #pragma unroll
    for (int j = 0; j < 12; ++j) acc[j] = 0.f;

    for (int kt = 0; kt < K/32; ++kt){
        // A stage: 32k x 16m = 128 float4, threads 0-127
        if (tid < 128){
            int kk = tid >> 2;
            int m4 = (tid & 3) * 4;
            int c  = kt*32 + kk;
            const float* pl;
            if (K > 192 && c >= 192) pl = A1 + ((size_t)b*192 + (c - 192))*NPIX;
            else                     pl = A0 + ((size_t)b*192 + c)*NPIX;
            float4 v = *(const float4*)&pl[n0 + m4];
            v.x = gelu_f(v.x); v.y = gelu_f(v.y); v.z = gelu_f(v.z); v.w = gelu_f(v.w);
            *(float4*)&lA[kk*20 + m4] = v;
        }
        // W stage: 32k x 192n direct b128 copies from WT
        #pragma unroll
        for (int r = 0; r < 6; ++r){
            int e  = tid + r*256;
            int kk = e / 48;
            int c4 = (e - kk*48) * 4;
            float4 v = *(const float4*)&WT[(size_t)(kt*32 + kk)*192 + c4];
            *(float4*)&lW[kk*196 + c4] = v;
        }
        __syncthreads();
        #pragma unroll
        for (int kk = 0; kk < 32; ++kk){
            float a  = lA[kk*20 + ty];
            float4 w0 = *(const float4*)&lW[kk*196 + tx*12];
            float4 w1 = *(const float4*)&lW[kk*196 + tx*12 + 4];
            float4 w2 = *(const float4*)&lW[kk*196 + tx*12 + 8];
            float wv[12] = {w0.x,w0.y,w0.z,w0.w, w1.x,w1.y,w1.z,w1.w, w2.x,w2.y,w2.z,w2.w};
            #pragma unroll
            for (int j = 0; j < 12; ++j)
                acc[j] = fmaf(a, wv[j], acc[j]);
        }
        __syncthreads();
    }

    const int lane = tid & 63;
    float es = expf(sptr[0]);
    float bv[12];
    #pragma unroll
    for (int q = 0; q < 3; ++q){
        float4 t4 = *(const float4*)&bias[tx*12 + q*4];
        bv[q*4+0] = t4.x; bv[q*4+1] = t4.y; bv[q*4+2] = t4.z; bv[q*4+3] = t4.w;
    }
    {
        float part = 0.f;
        #pragma unroll
        for (int j = 0; j < 12; ++j){
            float y = acc[j] + bv[j];
            acc[j] = y;
            if (!(tx == 0 && j == 0)) part += y * y;
        }
        #pragma unroll
        for (int m = 1; m < 16; m <<= 1) part += __shfl_xor(part, m, 64);
        float y0   = __shfl(acc[0], lane & 48, 64);   // tx==0 lane of this row
        float tval = es / (1.f + expf(-y0)) + 1.1f;
        float denom = fmaxf(part, 1e-8f);
        float sca  = (tval*tval - 1.f) / denom;
        float sqs  = sqrtf(sca);
        #pragma unroll
        for (int j = 0; j < 12; ++j){
            float o = acc[j] * sqs;
            if (tx == 0 && j == 0) o = tval;
            acc[j] = o;
        }
    }
    if (AX){
        #pragma unroll
        for (int j = 0; j < 12; ++j){
            int c = tx*12 + j;
            acc[j] += Xres[((size_t)b*192 + c)*NPIX + n0 + ty];
        }
    }
    if (AR){
        #pragma unroll
        for (int j = 0; j < 12; ++j){
            int c = tx*12 + j;
            acc[j] += Rcm[((size_t)b*192 + c)*NPIX + n0 + ty];
        }
    }
    #pragma unroll
    for (int j = 0; j < 12; ++j){
        int c = tx*12 + j;
        OutCM[((size_t)b*192 + c)*NPIX + n0 + ty] = acc[j];
    }
    if (DUAL){
        #pragma unroll
        for (int q = 0; q < 3; ++q){
            float4 o = make_float4(acc[q*4+0], acc[q*4+1], acc[q*4+2], acc[q*4+3]);
            *(float4*)&Hrm[((size_t)b*NPIX + n0 + ty)*192 + tx*12 + q*4] = o;
        }
    }
}

// ---------------------------------------------------------------------------
// conv: Hrm fp32 rows (stride 192) -> Xh/Xl fp16 hi/lo, S2 packed(-sq/2), SQf.
// ---------------------------------------------------------------------------
__device__ __forceinline__ unsigned pack2(float a, float b, unsigned &lo){
    union { _Float16 f; unsigned short u; } ha, hb, la, lb;
    ha.f = (_Float16)a; hb.f = (_Float16)b;
    float ra = a - (float)ha.f, rb = b - (float)hb.f;
    la.f = (_Float16)ra; lb.f = (_Float16)rb;
    lo = (unsigned)la.u | ((unsigned)lb.u << 16);
    return (unsigned)ha.u | ((unsigned)hb.u << 16);
}

__global__ __launch_bounds__(256) void conv_kernel(
    const float* __restrict__ H, unsigned short* __restrict__ Xh,
    unsigned short* __restrict__ Xl, unsigned* __restrict__ S2,
    float* __restrict__ SQf)
{
    const int tid = threadIdx.x;
    const int r = blockIdx.x*64 + (tid >> 2);
    const int b = r / NPAD, rl = r - b*NPAD;
    const int part = tid & 3;
    const size_t ob = ((size_t)b*NPAD + rl)*192 + part*48;

    if (rl < NPIX){
        const float* src = H + ((size_t)b*NPIX + rl)*192 + part*48;
        float s = 0.f;
        #pragma unroll
        for (int q = 0; q < 6; ++q){
            float4 v0 = *(const float4*)&src[q*8];
            float4 v1 = *(const float4*)&src[q*8 + 4];
            s = fmaf(v0.x,v0.x, fmaf(v0.y,v0.y, fmaf(v0.z,v0.z, fmaf(v0.w,v0.w, s))));
            s = fmaf(v1.x,v1.x, fmaf(v1.y,v1.y, fmaf(v1.z,v1.z, fmaf(v1.w,v1.w, s))));
            uint4 hv, lv;
            hv.x = pack2(v0.x, v0.y, lv.x);
            hv.y = pack2(v0.z, v0.w, lv.y);
            hv.z = pack2(v1.x, v1.y, lv.z);
            hv.w = pack2(v1.z, v1.w, lv.w);
            *(uint4*)&Xh[ob + q*8] = hv;
            *(uint4*)&Xl[ob + q*8] = lv;
        }
        s += __shfl_xor(s, 1, 64);
        s += __shfl_xor(s, 2, 64);
        if (part == 0){
            SQf[(size_t)b*NPIX + rl] = s;
            float s2 = -0.5f * s;
            union { _Float16 f; unsigned short u; } hh, ll;
            hh.f = (_Float16)s2;
            float rr = s2 - (float)hh.f;
            ll.f = (_Float16)rr;
            S2[(size_t)b*NPAD + rl] = (unsigned)hh.u | ((unsigned)ll.u << 16);
        }
    } else {
        uint4 z = make_uint4(0,0,0,0);
        #pragma unroll
        for (int q = 0; q < 6; ++q){
            *(uint4*)&Xh[ob + q*8] = z;
            *(uint4*)&Xl[ob + q*8] = z;
        }
        if (part == 0){
            union { _Float16 f; unsigned short u; } p;
            p.f = (_Float16)(-30000.0f);
            S2[(size_t)b*NPAD + rl] = (unsigned)p.u;
        }
    }
}

// ---------------------------------------------------------------------------
// MFMA kNN screen, NSP=4 splits.
// ---------------------------------------------------------------------------
__global__ __launch_bounds__(256) __attribute__((amdgpu_waves_per_eu(2))) void knn_kernel(
    const unsigned short* __restrict__ Xh, const unsigned short* __restrict__ Xl,
    const unsigned* __restrict__ S2, unsigned* __restrict__ PK)
{
    __shared__ uint4 lds[2560];

    const int tid  = threadIdx.x;
    const int lane = tid & 63;
    const int w    = tid >> 6;
    const int l31  = lane & 31;
    const int h    = lane >> 5;
    const int bid  = blockIdx.x;
    const int b    = bid & 7;
    const int t2   = bid >> 3;
    const int itile = t2 >> 2;
    const int sp    = t2 & 3;
    const int i0    = itile * 128;
    const int g0 = (sp*25)/NSP, g1 = ((sp+1)*25)/NSP;
    const size_t rowb = (size_t)b * NPAD;

    unsigned t_k0=0,t_k1=0,t_k2=0,t_k3=0,t_k4=0,t_k5=0,
             t_k6=0,t_k7=0,t_k8=0,t_k9=0,t_k10=0,t_k11=0;
    float thrf = -FINF;

    for (int g = g0; g < g1; ++g){
        const int jg = g*128;
        f32x16 acc0 = ZERO16, acc1 = ZERO16, acc2 = ZERO16, acc3 = ZERO16;

        for (int kc = 0; kc < 6; ++kc){
            __syncthreads();
            #pragma unroll
            for (int rr = 0; rr < 8; ++rr){
                int u   = tid + rr*256;
                int arr = u >> 9;
                int rs  = (u >> 2) & 127;
                int seg = u & 3;
                int row = (arr < 2) ? (jg + rs) : (i0 + rs);
                const unsigned short* sptr = (arr & 1) ? Xl : Xh;
                uint4 v = *(const uint4*)&sptr[(rowb + row)*192 + kc*32 + seg*8];
                lds[arr*640 + rs*5 + seg] = v;
            }
            __syncthreads();
            #pragma unroll
            for (int ks = 0; ks < 2; ++ks){
                int kq  = ks*2 + h;
                int rb  = l31*5 + kq;
                f16x8 bh = __builtin_bit_cast(f16x8, lds[1280 + w*160 + rb]);
                f16x8 bl = __builtin_bit_cast(f16x8, lds[1920 + w*160 + rb]);
                f16x8 a0h = __builtin_bit_cast(f16x8, lds[      0 + rb]);
                f16x8 a0l = __builtin_bit_cast(f16x8, lds[640 +   0 + rb]);
                MF(acc0, a0h, bh) MF(acc0, a0l, bh) MF(acc0, a0h, bl)
                f16x8 a1h = __builtin_bit_cast(f16x8, lds[      160 + rb]);
                f16x8 a1l = __builtin_bit_cast(f16x8, lds[640 + 160 + rb]);
                MF(acc1, a1h, bh) MF(acc1, a1l, bh) MF(acc1, a1h, bl)
                f16x8 a2h = __builtin_bit_cast(f16x8, lds[      320 + rb]);
                f16x8 a2l = __builtin_bit_cast(f16x8, lds[640 + 320 + rb]);
                MF(acc2, a2h, bh) MF(acc2, a2l, bh) MF(acc2, a2h, bl)
                f16x8 a3h = __builtin_bit_cast(f16x8, lds[      480 + rb]);
                f16x8 a3l = __builtin_bit_cast(f16x8, lds[640 + 480 + rb]);
                MF(acc3, a3h, bh) MF(acc3, a3l, bh) MF(acc3, a3h, bl)
            }
        }

        {
            unsigned m  = (h == 0) ? 0xFFFFFFFFu : 0u;
            unsigned om = 0x3C00u & m;
            f16x8 one = __builtin_bit_cast(f16x8, make_uint4(om, 0, 0, 0));
            unsigned s0 = S2[rowb + jg +  0 + l31];
            unsigned s1 = S2[rowb + jg + 32 + l31];
            unsigned s2 = S2[rowb + jg + 64 + l31];
            unsigned s3 = S2[rowb + jg + 96 + l31];
            f16x8 a;
            a = __builtin_bit_cast(f16x8, make_uint4((s0 & 0xFFFFu) & m, 0,0,0)); MF(acc0, a, one)
            a = __builtin_bit_cast(f16x8, make_uint4((s0 >> 16)     & m, 0,0,0)); MF(acc0, a, one)
            a = __builtin_bit_cast(f16x8, make_uint4((s1 & 0xFFFFu) & m, 0,0,0)); MF(acc1, a, one)
            a = __builtin_bit_cast(f16x8, make_uint4((s1 >> 16)     & m, 0,0,0)); MF(acc1, a, one)
            a = __builtin_bit_cast(f16x8, make_uint4((s2 & 0xFFFFu) & m, 0,0,0)); MF(acc2, a, one)
            a = __builtin_bit_cast(f16x8, make_uint4((s2 >> 16)     & m, 0,0,0)); MF(acc2, a, one)
            a = __builtin_bit_cast(f16x8, make_uint4((s3 & 0xFFFFu) & m, 0,0,0)); MF(acc3, a, one)
            a = __builtin_bit_cast(f16x8, make_uint4((s3 >> 16)     & m, 0,0,0)); MF(acc3, a, one)
        }

        INSACCK(acc0, 0)
        INSACCK(acc1, 1)
        INSACCK(acc2, 2)
        INSACCK(acc3, 3)
        thrf = (t_k11 != 0u) ? unmono(t_k11 & 0xFFFFF000u) : -FINF;
    }

    #define MRGK(Kk) { unsigned ok_ = __shfl((int)(Kk), lane ^ 32, 64); \
                      if (lane < 32) { INSKEY((unsigned)ok_) } }
    MRGK(t_k0) MRGK(t_k1) MRGK(t_k2) MRGK(t_k3) MRGK(t_k4) MRGK(t_k5)
    MRGK(t_k6) MRGK(t_k7) MRGK(t_k8) MRGK(t_k9) MRGK(t_k10) MRGK(t_k11)

    if (lane < 32){
        size_t po = ((size_t)(t2*8 + b)*128 + (size_t)w*32 + l31)*12;
        PK[po+ 0] = t_k0;  PK[po+ 1] = t_k1;  PK[po+ 2] = t_k2;  PK[po+ 3] = t_k3;
        PK[po+ 4] = t_k4;  PK[po+ 5] = t_k5;  PK[po+ 6] = t_k6;  PK[po+ 7] = t_k7;
        PK[po+ 8] = t_k8;  PK[po+ 9] = t_k9;  PK[po+10] = t_k10; PK[po+11] = t_k11;
    }
}

// ---------------------------------------------------------------------------
// 4-way key merge -> top-12 -> exact fp32 rescore -> top-9 -> max-message.
// ---------------------------------------------------------------------------
__global__ __launch_bounds__(256) void merge_msg_kernel(
    const float* __restrict__ H, const float* __restrict__ SQf,
    const unsigned* __restrict__ PK, float* __restrict__ Msg)
{
    __shared__ float liX[16*196];
    __shared__ unsigned kv[16*52];  // [16 rows][stride 52]: 4 lists x 12 keys
    __shared__ float cd[192];
    __shared__ int   cidx[192];
    __shared__ int   fidx[144];

    const int tid = threadIdx.x;
    const int bid = blockIdx.x;
    const int b  = bid / 196;
    const int i0 = (bid % 196) * 16;
    const int base = b * NPIX;

    #pragma unroll
    for (int k = 0; k < 3; ++k){
        int f = tid + k*256;
        int r = f / 48, c4 = f % 48;
        *(float4*)&liX[r*196 + c4*4] = *(const float4*)&H[(size_t)(base + i0 + r)*192 + c4*4];
    }
    if (tid < 64){
        int r = tid >> 2, sp = tid & 3;
        int i = i0 + r;
        size_t po = ((size_t)(((i>>7)*NSP + sp)*8 + b)*128 + (i & 127))*12;
        #pragma unroll
        for (int q = 0; q < 3; ++q)
            *(uint4*)&kv[r*52 + sp*12 + q*4] = *(const uint4*)&PK[po + q*4];
    }
    __syncthreads();

    if (tid < 16){
        int r = tid;
        int h0=0,h1=0,h2=0,h3=0;
        #pragma unroll
        for (int p = 0; p < 12; ++p){
            unsigned bk = 0; int bs = 0;
#define HEADC(SP,HV) { \
            unsigned k_ = (HV < 12) ? kv[r*52 + SP*12 + HV] : 0u; \
            bool bt_ = k_ > bk; \
            bk = bt_? k_ : bk; bs = bt_? SP : bs; }
            HEADC(0,h0) HEADC(1,h1) HEADC(2,h2) HEADC(3,h3)
#undef HEADC
            cidx[r*12 + p] = 4095 - (int)(bk & 0xFFFu);
            h0 += (bs==0); h1 += (bs==1); h2 += (bs==2); h3 += (bs==3);
        }
    }
    __syncthreads();

    if (tid < 192){
        int r = tid / 12, p = tid - r*12;
        int j = cidx[r*12 + p];
        const float* hj = &H[(size_t)(base + j)*192];
        float dot = 0.f;
        #pragma unroll
        for (int q = 0; q < 48; ++q){
            float4 xv = *(const float4*)&liX[r*196 + q*4];
            float4 yv = *(const float4*)&hj[q*4];
            dot = fmaf(xv.x,yv.x, fmaf(xv.y,yv.y, fmaf(xv.z,yv.z, fmaf(xv.w,yv.w, dot))));
        }
        cd[r*12 + p] = SQf[base + j] - 2.f*dot;
    }
    __syncthreads();

    if (tid < 16){
        int r = tid;
        Top9 m; m.init();
        #pragma unroll
        for (int c = 0; c < 12; ++c) m.insert(cd[r*12 + c], cidx[r*12 + c]);
        fidx[r*9+0]=m.j0; fidx[r*9+1]=m.j1; fidx[r*9+2]=m.j2; fidx[r*9+3]=m.j3;
        fidx[r*9+4]=m.j4; fidx[r*9+5]=m.j5; fidx[r*9+6]=m.j6; fidx[r*9+7]=m.j7;
        fidx[r*9+8]=m.j8;
    }
    __syncthreads();

    int rr = tid & 15, part = tid >> 4;
    int ii = i0 + rr;
    int nbr[9];
    #pragma unroll
    for (int e = 0; e < 9; ++e) nbr[e] = fidx[rr*9 + e];
    #pragma unroll
    for (int q = 0; q < 3; ++q){
        float4 mv = make_float4(-FINF, -FINF, -FINF, -FINF);
        #pragma unroll
        for (int e = 0; e < 9; ++e){
            float4 v = *(const float4*)&H[(size_t)(base + nbr[e])*192 + part*12 + q*4];
            mv.x = fmaxf(mv.x, v.x); mv.y = fmaxf(mv.y, v.y);
            mv.z = fmaxf(mv.z, v.z); mv.w = fmaxf(mv.w, v.w);
        }
        float4 xi = *(const float4*)&liX[rr*196 + part*12 + q*4];
        float m0 = mv.x - xi.x, m1 = mv.y - xi.y, m2 = mv.z - xi.z, m3 = mv.w - xi.w;
        int c = part*12 + q*4;
        Msg[((size_t)b*192 + c+0)*NPIX + ii] = m0;
        Msg[((size_t)b*192 + c+1)*NPIX + ii] = m1;
        Msg[((size_t)b*192 + c+2)*NPIX + ii] = m2;
        Msg[((size_t)b*192 + c+3)*NPIX + ii] = m3;
    }
}

extern "C" void kernel_launch(void* const* d_in, const int* in_sizes, int n_in,
                              void* d_out, int out_size, void* d_ws, size_t ws_size,
                              hipStream_t stream)
{
    const float* x  = (const float*)d_in[0];
    const float* W1 = (const float*)d_in[1];
    const float* b1 = (const float*)d_in[2];
    const float* s1 = (const float*)d_in[3];
    const float* W2 = (const float*)d_in[4];
    const float* b2 = (const float*)d_in[5];
    const float* s2 = (const float*)d_in[6];
    const float* Wg = (const float*)d_in[7];
    const float* bg = (const float*)d_in[8];
    const float* sg = (const float*)d_in[9];
    const float* W3 = (const float*)d_in[10];
    const float* b3 = (const float*)d_in[11];
    const float* s3 = (const float*)d_in[12];
    const float* W4 = (const float*)d_in[13];
    const float* b4 = (const float*)d_in[14];
    const float* s4 = (const float*)d_in[15];

    const size_t PL = (size_t)25088*192;
    float* Hrm  = (float*)d_ws;
    float* X1cm = Hrm  + PL;
    float* T1cm = X1cm + PL;
    float* X2cm = T1cm + PL;
    float* MXr  = X2cm + PL;
    unsigned short* Xh = (unsigned short*)MXr;
    unsigned short* Xl = Xh + (size_t)NB*NPAD*192;
    float* Msg = MXr;
    unsigned* S2p = (unsigned*)(MXr + (size_t)NB*NPAD*192/2*2);
    float* SQf = (float*)(S2p + (size_t)NB*NPAD);
    float* W1T = SQf + (size_t)NB*NPIX;
    float* W2T = W1T + 36864;
    float* WgT = W2T + 36864;
    float* W3T = WgT + 73728;
    float* W4T = W3T + 36864;
    unsigned* PK = (unsigned*)X2cm;          // 800*128*12 = 1.23M u32, consumed before LLg
    float* out = (float*)d_out;

    wt_kernel<<<216, 256, 0, stream>>>(W1, W2, Wg, W3, W4, W1T, W2T, WgT, W3T, W4T);
    // ffn_lorentz #1
    ll2_kernel<192, false, false, false><<<GRID_LL, 256, 0, stream>>>(x,    x,    W1T, b1, s1, nullptr, nullptr, T1cm, nullptr);
    ll2_kernel<192, true , true , false><<<GRID_LL, 256, 0, stream>>>(T1cm, T1cm, W2T, b2, s2, x,       nullptr, X1cm, Hrm);
    // graph conv
    conv_kernel<<<NB*NPAD/64, 256, 0, stream>>>(Hrm, Xh, Xl, S2p, SQf);
    knn_kernel<<<GRID_KNN, 256, 0, stream>>>(Xh, Xl, S2p, PK);
    merge_msg_kernel<<<GRID_MSG, 256, 0, stream>>>(Hrm, SQf, PK, Msg);
    ll2_kernel<384, false, false, false><<<GRID_LL, 256, 0, stream>>>(X1cm, Msg,  WgT, bg, sg, nullptr, nullptr, X2cm, nullptr);
    // ffn_lorentz #2 + final shortcut (output col-major = (B,C,H,W) native)
    ll2_kernel<192, false, false, false><<<GRID_LL, 256, 0, stream>>>(X2cm, X2cm, W3T, b3, s3, nullptr, nullptr, T1cm, nullptr);
    ll2_kernel<192, false, true , true ><<<GRID_LL, 256, 0, stream>>>(T1cm, T1cm, W4T, b4, s4, x,       X2cm,    out,  nullptr);
}

// Round 15
// 503.314 us; speedup vs baseline: 1.2775x; 1.2713x over previous
//
#include <hip/hip_runtime.h>
#include <math.h>

#define NB   8
#define NC   192
#define NPIX 3136
#define NPAD 3200
#define GRID_LL (NB*98)    // 784: M-tile 32 (R12 config)
#define NIT  25
#define NSP  8
#define GRID_KNN (NB*NIT*NSP)   // 1600
#define GRID_MSG (NB*196)  // 1568
#define FINF 3.4e38f

typedef _Float16 f16x8 __attribute__((ext_vector_type(8)));
typedef float   f32x16 __attribute__((ext_vector_type(16)));

__device__ __forceinline__ float gelu_f(float x){
    float u = 0.7978845608028654f * (x + 0.044715f * x * x * x);
    return 0.5f * x * (1.0f + tanhf(u));
}

// ---------------- min-lex top9 (exact rescore) ----------------
#define LESS9(da,ia,db,ib) ((da) < (db) || ((da) == (db) && (ia) < (ib)))
#define CSW9(a,ia,b,ib) { bool sw_ = LESS9(b,ib,a,ia); float tf_=(a); int ti_=(ia); \
    (a) = sw_? (b) : (a); (ia) = sw_? (ib) : (ia); (b) = sw_? tf_ : (b); (ib) = sw_? ti_ : (ib); }

struct Top9 {
    float d0,d1,d2,d3,d4,d5,d6,d7,d8;
    int   j0,j1,j2,j3,j4,j5,j6,j7,j8;
    __device__ __forceinline__ void init(){
        d0=d1=d2=d3=d4=d5=d6=d7=d8=FINF;
        j0=j1=j2=j3=j4=j5=j6=j7=j8=0x7FFFFFFF;
    }
    __device__ __forceinline__ void insert(float nd, int ni){
        if (!LESS9(nd, ni, d8, j8)) return;
        d8 = nd; j8 = ni;
        CSW9(d7,j7,d8,j8); CSW9(d6,j6,d7,j7); CSW9(d5,j5,d6,j6); CSW9(d4,j4,d5,j5);
        CSW9(d3,j3,d4,j4); CSW9(d2,j2,d3,j3); CSW9(d1,j1,d2,j2); CSW9(d0,j0,d1,j1);
    }
};

// ---------------- u32-key top12 (knn screen) ----------------
__device__ __forceinline__ unsigned f2mono(float e){
    unsigned u = __float_as_uint(e);
    return u ^ ((unsigned)((int)u >> 31) | 0x80000000u);
}
__device__ __forceinline__ float unmono(unsigned m){
    return __uint_as_float(m ^ ((unsigned)(((int)~m) >> 31) | 0x80000000u));
}

#define CSK(a,b) { unsigned h_ = (a) > (b) ? (a) : (b); unsigned l_ = (a) > (b) ? (b) : (a); (a) = h_; (b) = l_; }
#define INSKEY(x_) if ((x_) > t_k11){ t_k11 = (x_); \
    CSK(t_k10,t_k11) CSK(t_k9,t_k10) CSK(t_k8,t_k9) CSK(t_k7,t_k8) \
    CSK(t_k6,t_k7) CSK(t_k5,t_k6) CSK(t_k4,t_k5) CSK(t_k3,t_k4) \
    CSK(t_k2,t_k3) CSK(t_k1,t_k2) CSK(t_k0,t_k1) }

#define KQ(A,Q) { \
    unsigned q0_ = (f2mono(A[4*(Q)+0]) & 0xFFFFF000u) | (unsigned)(jinvb_ - 8*(Q)    ); \
    unsigned q1_ = (f2mono(A[4*(Q)+1]) & 0xFFFFF000u) | (unsigned)(jinvb_ - 8*(Q) - 1); \
    unsigned q2_ = (f2mono(A[4*(Q)+2]) & 0xFFFFF000u) | (unsigned)(jinvb_ - 8*(Q) - 2); \
    unsigned q3_ = (f2mono(A[4*(Q)+3]) & 0xFFFFF000u) | (unsigned)(jinvb_ - 8*(Q) - 3); \
    unsigned qa_ = q0_ > q1_ ? q0_ : q1_; \
    unsigned qb_ = q2_ > q3_ ? q2_ : q3_; \
    unsigned qm_ = qa_ > qb_ ? qa_ : qb_; \
    if (qm_ > t_k11){ INSKEY(q0_) INSKEY(q1_) INSKEY(q2_) INSKEY(q3_) } }

#define AMAX16(A) fmaxf(fmaxf(fmaxf(fmaxf(A[0],A[1]),fmaxf(A[2],A[3])),fmaxf(fmaxf(A[4],A[5]),fmaxf(A[6],A[7]))), \
                        fmaxf(fmaxf(fmaxf(A[8],A[9]),fmaxf(A[10],A[11])),fmaxf(fmaxf(A[12],A[13]),fmaxf(A[14],A[15]))))

#define INSACCK(A,JS) { float am_ = AMAX16(A); \
    if (am_ >= thrf){ int jinvb_ = 4095 - (jg + (JS)*32 + 4*h); \
        KQ(A,0) KQ(A,1) KQ(A,2) KQ(A,3) } }

#define MF(ACC,AO,BO) ACC = __builtin_amdgcn_mfma_f32_32x32x16_f16(AO,BO,ACC,0,0,0);
#define ZERO16 {0,0,0,0,0,0,0,0,0,0,0,0,0,0,0,0}

// ---------------------------------------------------------------------------
// Weight transpose: WT[k][n] = W[n][k]. 32x32 tiles via LDS.
// ---------------------------------------------------------------------------
__global__ __launch_bounds__(256) void wt_kernel(
    const float* __restrict__ W1, const float* __restrict__ W2,
    const float* __restrict__ Wg, const float* __restrict__ W3,
    const float* __restrict__ W4,
    float* __restrict__ W1T, float* __restrict__ W2T, float* __restrict__ WgT,
    float* __restrict__ W3T, float* __restrict__ W4T)
{
    __shared__ float tile[32*33];
    int t = blockIdx.x;
    const float* src; float* dst; int Kin;
    if (t < 36)      { src = W1; dst = W1T; Kin = 192; }
    else if (t < 72) { src = W2; dst = W2T; Kin = 192; t -= 36; }
    else if (t < 144){ src = Wg; dst = WgT; Kin = 384; t -= 72; }
    else if (t < 180){ src = W3; dst = W3T; Kin = 192; t -= 144; }
    else             { src = W4; dst = W4T; Kin = 192; t -= 180; }
    int ntc = Kin >> 5;
    int tr = t / ntc, tc = t - tr*ntc;
    int tid = threadIdx.x;
    {
        int i = tid >> 3, j4 = (tid & 7)*4;
        float4 v = *(const float4*)&src[(size_t)(tr*32 + i)*Kin + tc*32 + j4];
        tile[i*33 + j4+0] = v.x; tile[i*33 + j4+1] = v.y;
        tile[i*33 + j4+2] = v.z; tile[i*33 + j4+3] = v.w;
    }
    __syncthreads();
    {
        int j = tid >> 3, i4 = (tid & 7)*4;
        float4 o = make_float4(tile[(i4+0)*33 + j], tile[(i4+1)*33 + j],
                               tile[(i4+2)*33 + j], tile[(i4+3)*33 + j]);
        *(float4*)&dst[(size_t)(tc*32 + j)*192 + tr*32 + i4] = o;
    }
}

// ---------------------------------------------------------------------------
// Fused GEMM + lorentz_linear, col-major activations (exact R12 version).
// ---------------------------------------------------------------------------
template<int K, bool DUAL, bool AX, bool AR>
__global__ __launch_bounds__(256, 4) void ll2_kernel(
    const float* __restrict__ A0, const float* __restrict__ A1,
    const float* __restrict__ WT, const float* __restrict__ bias,
    const float* __restrict__ sptr, const float* __restrict__ Xres,
    const float* __restrict__ Rcm,
    float* __restrict__ OutCM, float* __restrict__ Hrm)
{
    __shared__ float lA[32*36];    // [kk][mm]
    __shared__ float lW[32*196];   // [kk][nn]

    const int tid = threadIdx.x;
    const int tx = tid & 15, ty = tid >> 4;
    const int bid = blockIdx.x;
    const int b  = bid / 98;
    const int n0 = (bid % 98) * 32;

    float acc[2][12];
    #pragma unroll
    for (int mi = 0; mi < 2; ++mi)
        #pragma unroll
        for (int j = 0; j < 12; ++j) acc[mi][j] = 0.f;

    for (int kt = 0; kt < K/32; ++kt){
        {
            int kk = tid >> 3;
            int m4 = (tid & 7) * 4;
            int c  = kt*32 + kk;
            const float* pl;
            if (K > 192 && c >= 192) pl = A1 + ((size_t)b*192 + (c - 192))*NPIX;
            else                     pl = A0 + ((size_t)b*192 + c)*NPIX;
            float4 v = *(const float4*)&pl[n0 + m4];
            v.x = gelu_f(v.x); v.y = gelu_f(v.y); v.z = gelu_f(v.z); v.w = gelu_f(v.w);
            *(float4*)&lA[kk*36 + m4] = v;
        }
        #pragma unroll
        for (int r = 0; r < 6; ++r){
            int e  = tid + r*256;
            int kk = e / 48;
            int c4 = (e - kk*48) * 4;
            float4 v = *(const float4*)&WT[(size_t)(kt*32 + kk)*192 + c4];
            *(float4*)&lW[kk*196 + c4] = v;
        }
        __syncthreads();
        #pragma unroll
        for (int kk = 0; kk < 32; ++kk){
            float2 a2 = *(const float2*)&lA[kk*36 + ty*2];
            float4 w0 = *(const float4*)&lW[kk*196 + tx*12];
            float4 w1 = *(const float4*)&lW[kk*196 + tx*12 + 4];
            float4 w2 = *(const float4*)&lW[kk*196 + tx*12 + 8];
            float aw[2]  = {a2.x, a2.y};
            float wv[12] = {w0.x,w0.y,w0.z,w0.w, w1.x,w1.y,w1.z,w1.w, w2.x,w2.y,w2.z,w2.w};
            #pragma unroll
            for (int mi = 0; mi < 2; ++mi)
                #pragma unroll
                for (int j = 0; j < 12; ++j)
                    acc[mi][j] = fmaf(aw[mi], wv[j], acc[mi][j]);
        }
        __syncthreads();
    }

    const int lane = tid & 63;
    float es = expf(sptr[0]);
    float bv[12];
    #pragma unroll
    for (int q = 0; q < 3; ++q){
        float4 t4 = *(const float4*)&bias[tx*12 + q*4];
        bv[q*4+0] = t4.x; bv[q*4+1] = t4.y; bv[q*4+2] = t4.z; bv[q*4+3] = t4.w;
    }
    #pragma unroll
    for (int mi = 0; mi < 2; ++mi){
        float part = 0.f;
        #pragma unroll
        for (int j = 0; j < 12; ++j){
            float y = acc[mi][j] + bv[j];
            acc[mi][j] = y;
            if (!(tx == 0 && j == 0)) part += y * y;
        }
        #pragma unroll
        for (int m = 1; m < 16; m <<= 1) part += __shfl_xor(part, m, 64);
        float y0   = __shfl(acc[mi][0], lane & 48, 64);
        float tval = es / (1.f + expf(-y0)) + 1.1f;
        float denom = fmaxf(part, 1e-8f);
        float sca  = (tval*tval - 1.f) / denom;
        float sqs  = sqrtf(sca);
        #pragma unroll
        for (int j = 0; j < 12; ++j){
            float o = acc[mi][j] * sqs;
            if (tx == 0 && j == 0) o = tval;
            acc[mi][j] = o;
        }
    }
    if (AX){
        #pragma unroll
        for (int j = 0; j < 12; ++j){
            int c = tx*12 + j;
            float2 xv = *(const float2*)&Xres[((size_t)b*192 + c)*NPIX + n0 + ty*2];
            acc[0][j] += xv.x; acc[1][j] += xv.y;
        }
    }
    if (AR){
        #pragma unroll
        for (int j = 0; j < 12; ++j){
            int c = tx*12 + j;
            float2 rv = *(const float2*)&Rcm[((size_t)b*192 + c)*NPIX + n0 + ty*2];
            acc[0][j] += rv.x; acc[1][j] += rv.y;
        }
    }
    #pragma unroll
    for (int j = 0; j < 12; ++j){
        int c = tx*12 + j;
        *(float2*)&OutCM[((size_t)b*192 + c)*NPIX + n0 + ty*2] = make_float2(acc[0][j], acc[1][j]);
    }
    if (DUAL){
        #pragma unroll
        for (int mi = 0; mi < 2; ++mi){
            #pragma unroll
            for (int q = 0; q < 3; ++q){
                float4 o = make_float4(acc[mi][q*4+0], acc[mi][q*4+1], acc[mi][q*4+2], acc[mi][q*4+3]);
                *(float4*)&Hrm[((size_t)b*NPIX + n0 + ty*2 + mi)*192 + tx*12 + q*4] = o;
            }
        }
    }
}

// ---------------------------------------------------------------------------
// conv: Hrm fp32 rows -> Xh fp16-hi only, S2h fp16(-sq/2), SQf fp32.
// Pad rows: Xh=0, S2h=fp16(-30000).
// ---------------------------------------------------------------------------
__device__ __forceinline__ unsigned pack_hi(float a, float b){
    union { _Float16 f; unsigned short u; } ha, hb;
    ha.f = (_Float16)a; hb.f = (_Float16)b;
    return (unsigned)ha.u | ((unsigned)hb.u << 16);
}

__global__ __launch_bounds__(256) void conv_kernel(
    const float* __restrict__ H, unsigned short* __restrict__ Xh,
    unsigned short* __restrict__ S2h, float* __restrict__ SQf)
{
    const int tid = threadIdx.x;
    const int r = blockIdx.x*64 + (tid >> 2);
    const int b = r / NPAD, rl = r - b*NPAD;
    const int part = tid & 3;
    const size_t ob = ((size_t)b*NPAD + rl)*192 + part*48;

    if (rl < NPIX){
        const float* src = H + ((size_t)b*NPIX + rl)*192 + part*48;
        float s = 0.f;
        #pragma unroll
        for (int q = 0; q < 6; ++q){
            float4 v0 = *(const float4*)&src[q*8];
            float4 v1 = *(const float4*)&src[q*8 + 4];
            s = fmaf(v0.x,v0.x, fmaf(v0.y,v0.y, fmaf(v0.z,v0.z, fmaf(v0.w,v0.w, s))));
            s = fmaf(v1.x,v1.x, fmaf(v1.y,v1.y, fmaf(v1.z,v1.z, fmaf(v1.w,v1.w, s))));
            uint4 hv;
            hv.x = pack_hi(v0.x, v0.y);
            hv.y = pack_hi(v0.z, v0.w);
            hv.z = pack_hi(v1.x, v1.y);
            hv.w = pack_hi(v1.z, v1.w);
            *(uint4*)&Xh[ob + q*8] = hv;
        }
        s += __shfl_xor(s, 1, 64);
        s += __shfl_xor(s, 2, 64);
        if (part == 0){
            SQf[(size_t)b*NPIX + rl] = s;
            union { _Float16 f; unsigned short u; } hh;
            hh.f = (_Float16)(-0.5f * s);
            S2h[(size_t)b*NPAD + rl] = hh.u;
        }
    } else {
        uint4 z = make_uint4(0,0,0,0);
        #pragma unroll
        for (int q = 0; q < 6; ++q)
            *(uint4*)&Xh[ob + q*8] = z;
        if (part == 0){
            union { _Float16 f; unsigned short u; } p;
            p.f = (_Float16)(-30000.0f);
            S2h[(size_t)b*NPAD + rl] = p.u;
        }
    }
}

// ---------------------------------------------------------------------------
// MFMA kNN screen, 1-pass fp16-hi (exact rescore downstream absorbs the
// screen error; merged top-16 rescored). NSP=8, LDS 20KB.
// ---------------------------------------------------------------------------
__global__ __launch_bounds__(256) __attribute__((amdgpu_waves_per_eu(2))) void knn_kernel(
    const unsigned short* __restrict__ Xh, const unsigned short* __restrict__ S2h,
    unsigned* __restrict__ PK)
{
    __shared__ uint4 lds[1280];   // 2 arrays (A=j rows, B=i rows) x 128 rows x stride-5

    const int tid  = threadIdx.x;
    const int lane = tid & 63;
    const int w    = tid >> 6;
    const int l31  = lane & 31;
    const int h    = lane >> 5;
    const int bid  = blockIdx.x;
    const int b    = bid & 7;
    const int t2   = bid >> 3;
    const int itile = t2 >> 3;
    const int sp    = t2 & 7;
    const int i0    = itile * 128;
    const int g0 = (sp*25)/NSP, g1 = ((sp+1)*25)/NSP;
    const size_t rowb = (size_t)b * NPAD;

    unsigned t_k0=0,t_k1=0,t_k2=0,t_k3=0,t_k4=0,t_k5=0,
             t_k6=0,t_k7=0,t_k8=0,t_k9=0,t_k10=0,t_k11=0;
    float thrf = -FINF;

    for (int g = g0; g < g1; ++g){
        const int jg = g*128;
        f32x16 acc0 = ZERO16, acc1 = ZERO16, acc2 = ZERO16, acc3 = ZERO16;

        for (int kc = 0; kc < 6; ++kc){
            __syncthreads();
            #pragma unroll
            for (int rr = 0; rr < 4; ++rr){
                int u   = tid + rr*256;
                int arr = u >> 9;
                int rs  = (u >> 2) & 127;
                int seg = u & 3;
                int row = (arr == 0) ? (jg + rs) : (i0 + rs);
                uint4 v = *(const uint4*)&Xh[(rowb + row)*192 + kc*32 + seg*8];
                lds[arr*640 + rs*5 + seg] = v;
            }
            __syncthreads();
            #pragma unroll
            for (int ks = 0; ks < 2; ++ks){
                int kq  = ks*2 + h;
                int rb  = l31*5 + kq;
                f16x8 bh = __builtin_bit_cast(f16x8, lds[640 + w*160 + rb]);
                f16x8 a0h = __builtin_bit_cast(f16x8, lds[  0 + rb]);
                f16x8 a1h = __builtin_bit_cast(f16x8, lds[160 + rb]);
                f16x8 a2h = __builtin_bit_cast(f16x8, lds[320 + rb]);
                f16x8 a3h = __builtin_bit_cast(f16x8, lds[480 + rb]);
                MF(acc0, a0h, bh)
                MF(acc1, a1h, bh)
                MF(acc2, a2h, bh)
                MF(acc3, a3h, bh)
            }
        }

        // k=192 channel: A = -sq_j/2 (hi), B = 1 at k-elem 0 (h==0 lanes)
        {
            unsigned m  = (h == 0) ? 0xFFFFFFFFu : 0u;
            unsigned om = 0x3C00u & m;
            f16x8 one = __builtin_bit_cast(f16x8, make_uint4(om, 0, 0, 0));
            unsigned s0 = (unsigned)S2h[rowb + jg +  0 + l31];
            unsigned s1 = (unsigned)S2h[rowb + jg + 32 + l31];
            unsigned s2 = (unsigned)S2h[rowb + jg + 64 + l31];
            unsigned s3 = (unsigned)S2h[rowb + jg + 96 + l31];
            f16x8 a;
            a = __builtin_bit_cast(f16x8, make_uint4(s0 & m, 0,0,0)); MF(acc0, a, one)
            a = __builtin_bit_cast(f16x8, make_uint4(s1 & m, 0,0,0)); MF(acc1, a, one)
            a = __builtin_bit_cast(f16x8, make_uint4(s2 & m, 0,0,0)); MF(acc2, a, one)
            a = __builtin_bit_cast(f16x8, make_uint4(s3 & m, 0,0,0)); MF(acc3, a, one)
        }

        INSACCK(acc0, 0)
        INSACCK(acc1, 1)
        INSACCK(acc2, 2)
        INSACCK(acc3, 3)
        thrf = (t_k11 != 0u) ? unmono(t_k11 & 0xFFFFF000u) : -FINF;
    }

    #define MRGK(Kk) { unsigned ok_ = __shfl((int)(Kk), lane ^ 32, 64); \
                      if (lane < 32) { INSKEY((unsigned)ok_) } }
    MRGK(t_k0) MRGK(t_k1) MRGK(t_k2) MRGK(t_k3) MRGK(t_k4) MRGK(t_k5)
    MRGK(t_k6) MRGK(t_k7) MRGK(t_k8) MRGK(t_k9) MRGK(t_k10) MRGK(t_k11)

    if (lane < 32){
        size_t po = ((size_t)(t2*8 + b)*128 + (size_t)w*32 + l31)*12;
        PK[po+ 0] = t_k0;  PK[po+ 1] = t_k1;  PK[po+ 2] = t_k2;  PK[po+ 3] = t_k3;
        PK[po+ 4] = t_k4;  PK[po+ 5] = t_k5;  PK[po+ 6] = t_k6;  PK[po+ 7] = t_k7;
        PK[po+ 8] = t_k8;  PK[po+ 9] = t_k9;  PK[po+10] = t_k10; PK[po+11] = t_k11;
    }
}

// ---------------------------------------------------------------------------
// 8-way key merge -> approx top-16 -> exact fp32 rescore of 16 -> top-9
// -> max-message (col-major Msg).
// ---------------------------------------------------------------------------
__global__ __launch_bounds__(256) void merge_msg_kernel(
    const float* __restrict__ H, const float* __restrict__ SQf,
    const unsigned* __restrict__ PK, float* __restrict__ Msg)
{
    __shared__ float liX[16*196];
    __shared__ unsigned kv[1600];   // [16 rows][stride 100]: 8 lists x 12 keys
    __shared__ float cd[256];
    __shared__ int   cidx[256];
    __shared__ int   fidx[144];

    const int tid = threadIdx.x;
    const int bid = blockIdx.x;
    const int b  = bid / 196;
    const int i0 = (bid % 196) * 16;
    const int base = b * NPIX;

    #pragma unroll
    for (int k = 0; k < 3; ++k){
        int f = tid + k*256;
        int r = f / 48, c4 = f % 48;
        *(float4*)&liX[r*196 + c4*4] = *(const float4*)&H[(size_t)(base + i0 + r)*192 + c4*4];
    }
    if (tid < 128){
        int r = tid >> 3, sp = tid & 7;
        int i = i0 + r;
        size_t po = ((size_t)(((i>>7)*NSP + sp)*8 + b)*128 + (i & 127))*12;
        #pragma unroll
        for (int q = 0; q < 3; ++q)
            *(uint4*)&kv[r*100 + sp*12 + q*4] = *(const uint4*)&PK[po + q*4];
    }
    __syncthreads();

    if (tid < 16){
        int r = tid;
        int h0=0,h1=0,h2=0,h3=0,h4=0,h5=0,h6=0,h7=0;
        #pragma unroll
        for (int p = 0; p < 16; ++p){
            unsigned bk = 0; int bs = 0;
#define HEADC(SP,HV) { \
            unsigned k_ = (HV < 12) ? kv[r*100 + SP*12 + HV] : 0u; \
            bool bt_ = k_ > bk; \
            bk = bt_? k_ : bk; bs = bt_? SP : bs; }
            HEADC(0,h0) HEADC(1,h1) HEADC(2,h2) HEADC(3,h3)
            HEADC(4,h4) HEADC(5,h5) HEADC(6,h6) HEADC(7,h7)
#undef HEADC
            cidx[r*16 + p] = 4095 - (int)(bk & 0xFFFu);
            h0 += (bs==0); h1 += (bs==1); h2 += (bs==2); h3 += (bs==3);
            h4 += (bs==4); h5 += (bs==5); h6 += (bs==6); h7 += (bs==7);
        }
    }
    __syncthreads();

    {
        int r = tid >> 4, p = tid & 15;
        int j = cidx[r*16 + p];
        const float* hj = &H[(size_t)(base + j)*192];
        float dot = 0.f;
        #pragma unroll
        for (int q = 0; q < 48; ++q){
            float4 xv = *(const float4*)&liX[r*196 + q*4];
            float4 yv = *(const float4*)&hj[q*4];
            dot = fmaf(xv.x,yv.x, fmaf(xv.y,yv.y, fmaf(xv.z,yv.z, fmaf(xv.w,yv.w, dot))));
        }
        cd[r*16 + p] = SQf[base + j] - 2.f*dot;
    }
    __syncthreads();

    if (tid < 16){
        int r = tid;
        Top9 m; m.init();
        #pragma unroll
        for (int c = 0; c < 16; ++c) m.insert(cd[r*16 + c], cidx[r*16 + c]);
        fidx[r*9+0]=m.j0; fidx[r*9+1]=m.j1; fidx[r*9+2]=m.j2; fidx[r*9+3]=m.j3;
        fidx[r*9+4]=m.j4; fidx[r*9+5]=m.j5; fidx[r*9+6]=m.j6; fidx[r*9+7]=m.j7;
        fidx[r*9+8]=m.j8;
    }
    __syncthreads();

    int rr = tid & 15, part = tid >> 4;
    int ii = i0 + rr;
    int nbr[9];
    #pragma unroll
    for (int e = 0; e < 9; ++e) nbr[e] = fidx[rr*9 + e];
    #pragma unroll
    for (int q = 0; q < 3; ++q){
        float4 mv = make_float4(-FINF, -FINF, -FINF, -FINF);
        #pragma unroll
        for (int e = 0; e < 9; ++e){
            float4 v = *(const float4*)&H[(size_t)(base + nbr[e])*192 + part*12 + q*4];
            mv.x = fmaxf(mv.x, v.x); mv.y = fmaxf(mv.y, v.y);
            mv.z = fmaxf(mv.z, v.z); mv.w = fmaxf(mv.w, v.w);
        }
        float4 xi = *(const float4*)&liX[rr*196 + part*12 + q*4];
        float m0 = mv.x - xi.x, m1 = mv.y - xi.y, m2 = mv.z - xi.z, m3 = mv.w - xi.w;
        int c = part*12 + q*4;
        Msg[((size_t)b*192 + c+0)*NPIX + ii] = m0;
        Msg[((size_t)b*192 + c+1)*NPIX + ii] = m1;
        Msg[((size_t)b*192 + c+2)*NPIX + ii] = m2;
        Msg[((size_t)b*192 + c+3)*NPIX + ii] = m3;
    }
}

extern "C" void kernel_launch(void* const* d_in, const int* in_sizes, int n_in,
                              void* d_out, int out_size, void* d_ws, size_t ws_size,
                              hipStream_t stream)
{
    const float* x  = (const float*)d_in[0];
    const float* W1 = (const float*)d_in[1];
    const float* b1 = (const float*)d_in[2];
    const float* s1 = (const float*)d_in[3];
    const float* W2 = (const float*)d_in[4];
    const float* b2 = (const float*)d_in[5];
    const float* s2 = (const float*)d_in[6];
    const float* Wg = (const float*)d_in[7];
    const float* bg = (const float*)d_in[8];
    const float* sg = (const float*)d_in[9];
    const float* W3 = (const float*)d_in[10];
    const float* b3 = (const float*)d_in[11];
    const float* s3 = (const float*)d_in[12];
    const float* W4 = (const float*)d_in[13];
    const float* b4 = (const float*)d_in[14];
    const float* s4 = (const float*)d_in[15];

    const size_t PL = (size_t)25088*192;
    float* Hrm  = (float*)d_ws;
    float* X1cm = Hrm  + PL;
    float* T1cm = X1cm + PL;
    float* X2cm = T1cm + PL;
    float* MXr  = X2cm + PL;                          // Xh fp16 -> later Msg col-major
    unsigned short* Xh = (unsigned short*)MXr;        // [8][3200][192] ushort = 4.92M floats
    float* Msg = MXr;                                 // aliases Xh after knn
    unsigned short* S2h = (unsigned short*)(MXr + PL);// [8][3200] ushort
    float* SQf = (float*)(S2h + (size_t)NB*NPAD);
    float* W1T = SQf + (size_t)NB*NPIX;
    float* W2T = W1T + 36864;
    float* WgT = W2T + 36864;
    float* W3T = WgT + 73728;
    float* W4T = W3T + 36864;
    unsigned* PK = (unsigned*)X2cm;                   // 1600*128*12 = 2.46M u32, consumed before LLg
    float* out = (float*)d_out;

    wt_kernel<<<216, 256, 0, stream>>>(W1, W2, Wg, W3, W4, W1T, W2T, WgT, W3T, W4T);
    // ffn_lorentz #1
    ll2_kernel<192, false, false, false><<<GRID_LL, 256, 0, stream>>>(x,    x,    W1T, b1, s1, nullptr, nullptr, T1cm, nullptr);
    ll2_kernel<192, true , true , false><<<GRID_LL, 256, 0, stream>>>(T1cm, T1cm, W2T, b2, s2, x,       nullptr, X1cm, Hrm);
    // graph conv
    conv_kernel<<<NB*NPAD/64, 256, 0, stream>>>(Hrm, Xh, S2h, SQf);
    knn_kernel<<<GRID_KNN, 256, 0, stream>>>(Xh, S2h, PK);
    merge_msg_kernel<<<GRID_MSG, 256, 0, stream>>>(Hrm, SQf, PK, Msg);
    ll2_kernel<384, false, false, false><<<GRID_LL, 256, 0, stream>>>(X1cm, Msg,  WgT, bg, sg, nullptr, nullptr, X2cm, nullptr);
    // ffn_lorentz #2 + final shortcut (output col-major = (B,C,H,W) native)
    ll2_kernel<192, false, false, false><<<GRID_LL, 256, 0, stream>>>(X2cm, X2cm, W3T, b3, s3, nullptr, nullptr, T1cm, nullptr);
    ll2_kernel<192, false, true , true ><<<GRID_LL, 256, 0, stream>>>(T1cm, T1cm, W4T, b4, s4, x,       X2cm,    out,  nullptr);
}